// Round 9
// baseline (587.330 us; speedup 1.0000x reference)
//
#include <hip/hip_runtime.h>
#include <stdint.h>

typedef float f32x4 __attribute__((ext_vector_type(4)));
typedef int   i32x4 __attribute__((ext_vector_type(4)));
typedef int   i32x8 __attribute__((ext_vector_type(8)));
typedef unsigned int u32;

#define NSTEPS 499
#define LEN    128
#define HID    512
#define TROW   64000   // 500*128

union frag32 { i32x8 v; u32 u[8]; i32x4 h[2]; };
union fvec4  { f32x4 v; float f[4]; };

// Opaque register pin: value becomes asm output -> cannot be rematerialized
// or sunk into the loop; must stay live in VGPRs/AGPRs.
#define PIN_FRAG32(fr) asm volatile("" : "+v"((fr).u[0]), "+v"((fr).u[1]), \
                                         "+v"((fr).u[2]), "+v"((fr).u[3]), \
                                         "+v"((fr).u[4]), "+v"((fr).u[5]), \
                                         "+v"((fr).u[6]), "+v"((fr).u[7]))
#define PIN_F4(fv)    asm volatile("" : "+v"((fv).f[0]), "+v"((fv).f[1]), \
                                        "+v"((fv).f[2]), "+v"((fv).f[3]))

// pack 2 f32 -> 2 fp8 e4m3 (RNE, saturating) into low/high word of old.
// HI must be a compile-time constant (builtin requires literal op_sel).
template <bool HI>
__device__ __forceinline__ u32 cvt2_fp8(float a, float b, u32 old) {
  return (u32)__builtin_amdgcn_cvt_pk_fp8_f32(a, b, (int)old, HI);
}

// One WG = 512 thr = 8 waves = 2 waves/SIMD owns 16 batch rows for all steps.
// BOTH layers MX-scaled fp8 MFMA (unit e8m0 scales = exact), weights pinned
// in VGPRs. Exact power-of-2 scaling: a1 x32, a2 x64, descale -DT/2048.
//
// vs 376us version (VALU/critical-path polish):
//  - Euler-Maruyama update folded into L2 accumulator init: acc2[0] starts
//    at P = (C0*xm + SD*eps + nb2) * (1/NS), computed in the L1 phase (off
//    the critical path). Epilogue is just xn = NS*(acc2[0]+acc2[1]).
//    Error: P ~ 6e6, score ~ 1e3 -> abs err ~ NS*1 = 5e-7, negligible.
//  - post-bar1 is a pure burst: 8x ds_read_b128 then 4 MFMAs, zero VALU
//    in between; kills acc zero-init traffic.
//
// Uniform fp8 LDS layout (x and h), 16B-granular:
//   element (k, m) at byte (((k>>4)*16 + m)*16 + (k&15))
// Writes lane-linear conflict-free; reads 2 lanes/bank = free.
// K-slot consistency: A-frags packed from global with the same k-order
// (k = 32q + (i>>2)*16 + (i&3)*4 + byte) -> per-lane k permutation cancels
// in the dot product (reduction dim).
__global__ __launch_bounds__(512, 2)
void cond_diff_kernel(const float* __restrict__ fd,
                      const float* __restrict__ W1,
                      const float* __restrict__ b1,
                      const float* __restrict__ W2,
                      const float* __restrict__ b2,
                      const float* __restrict__ noise,
                      float* __restrict__ out)
{
  const int tid  = threadIdx.x;
  const int w    = tid >> 6;     // wave 0..7
  const int lane = tid & 63;
  const int q    = lane >> 4;    // quad 0..3
  const int lc   = lane & 15;
  const int bb   = blockIdx.x << 4;

  __shared__ u32 xq[512];        // x fp8, 2 KB: (k>>4, m) 16B slots
  __shared__ u32 hq[2048];       // h fp8, 8 KB: (k>>4, m) 16B slots
  unsigned char* const xqp = (unsigned char*)xq;
  unsigned char* const hqp = (unsigned char*)hq;

  // ---- layer1 A-frags: fp8(32*W1), rows j=64w+16t+lc, k-order as B ----
  frag32 a1s[4];
#pragma unroll
  for (int t = 0; t < 4; ++t) {
    const int j = 64 * w + 16 * t + lc;
#pragma unroll
    for (int i = 0; i < 8; ++i) {
      const int kb = 32 * q + (i >> 2) * 16 + (i & 3) * 4;
      u32 u0 = cvt2_fp8<false>(32.f * W1[(kb + 0) * HID + j],
                               32.f * W1[(kb + 1) * HID + j], 0u);
      u0     = cvt2_fp8<true >(32.f * W1[(kb + 2) * HID + j],
                               32.f * W1[(kb + 3) * HID + j], u0);
      a1s[t].u[i] = u0;
    }
    PIN_FRAG32(a1s[t]);
  }
  // ---- layer2 A-frags: fp8(64*W2), own l-tile (w), K=512 in 4 frags ----
  frag32 a2s[4];
#pragma unroll
  for (int f = 0; f < 4; ++f) {
#pragma unroll
    for (int i = 0; i < 8; ++i) {
      const int kb = 128 * f + 32 * q + (i >> 2) * 16 + (i & 3) * 4;
      const float* wp = W2 + 16 * w + lc;
      u32 u0 = cvt2_fp8<false>(64.f * wp[(kb + 0) * LEN],
                               64.f * wp[(kb + 1) * LEN], 0u);
      u0     = cvt2_fp8<true >(64.f * wp[(kb + 2) * LEN],
                               64.f * wp[(kb + 3) * LEN], u0);
      a2s[f].u[i] = u0;
    }
    PIN_FRAG32(a2s[f]);
  }

  // ---- biases in C/D layout (rows j0+r, col lc), x32, PINNED ----
  fvec4 bb1[4], bw1[4];
#pragma unroll
  for (int t = 0; t < 4; ++t) {
    const int j0 = 64 * w + 16 * t + 4 * q;
    f32x4 b1v = *(const f32x4*)(b1 + j0);
    f32x4 w1t = *(const f32x4*)(W1 + 128 * HID + j0);   // time row of W1
#pragma unroll
    for (int r = 0; r < 4; ++r) { bb1[t].f[r] = 32.f * b1v[r]; bw1[t].f[r] = 32.f * w1t[r]; }
    PIN_F4(bb1[t]); PIN_F4(bw1[t]);
  }
  const int l0 = 16 * w + 4 * q;           // owned output rows (tile == w)
  fvec4 nb2;
  {
    f32x4 b2v = *(const f32x4*)(b2 + l0);
#pragma unroll
    for (int r = 0; r < 4; ++r) nb2.f[r] = -0.001f * b2v[r];
    PIN_F4(nb2);
  }

  // loop-invariant LDS addresses
  unsigned char* const xw_p = xqp + w * 256 + lc * 16 + 4 * q;   // x fp8 write
  unsigned char* const hw_p = hqp + w * 1024 + lc * 16 + 4 * q;  // h fp8 write (+t*256)
  const unsigned char* const rd_p = hqp + q * 512 + lc * 16;     // h read base (+f*2048,+256)
  const unsigned char* const xr_p = xqp + q * 512 + lc * 16;     // x read base (+256)

  // ---- x0 = fd[:, 499, :]; fp32 master state (rows l0+r, col batch=lc) ----
  const int obase = (bb + lc) * TROW;
  f32x4 xm = *(const f32x4*)(fd + obase + NSTEPS * LEN + l0);
  *(f32x4*)(out + obase + l0) = xm;                 // out[:, 0, :] = x0
  {
    u32 xw0 = cvt2_fp8<false>(xm[0], xm[1], 0u);
    xw0     = cvt2_fp8<true >(xm[2], xm[3], xw0);
    *(u32*)xw_p = xw0;
  }
  __syncthreads();

  const float DTc = 0.001f;
  const float SD  = 0.031622776601683794f;  // sqrt(DT)
  const float C0  = 0.9995f;                // 1 - 0.5*DT
  const float NS  = -0.001f / 2048.0f;      // -DT / (32*64) descale
  const float INV_NS = 1.0f / (-0.001f / 2048.0f);
  const int   SC1 = 0x7F7F7F7F;             // e8m0 unit scales (2^0) x4 blocks

#pragma unroll 1
  for (int k = 0; k < NSTEPS; ++k) {
    const float tt = DTc * (float)(NSTEPS - k);

    f32x4 eps = *(const f32x4*)(noise + k * LEN + l0);  // prefetch

    // ---- layer 1 (MX fp8, K=128): 2 reads + 4 scaled MFMAs ----
    f32x4 acc1[4];
#pragma unroll
    for (int t = 0; t < 4; ++t)
#pragma unroll
      for (int r = 0; r < 4; ++r)
        acc1[t][r] = __builtin_fmaf(tt, bw1[t].f[r], bb1[t].f[r]);
    {
      frag32 bx;
      bx.h[0] = *(const i32x4*)(xr_p);
      bx.h[1] = *(const i32x4*)(xr_p + 256);
#pragma unroll
      for (int t = 0; t < 4; ++t)
        acc1[t] = __builtin_amdgcn_mfma_scale_f32_16x16x128_f8f6f4(
                    a1s[t].v, bx.v, acc1[t], 0, 0, 0, SC1, 0, SC1);
    }

    // ---- update-base P (off critical path; uses current xm + eps):
    //      P = (C0*xm + SD*eps + nb2) / NS  -> acc2[0] initial value ----
    f32x4 P;
#pragma unroll
    for (int r = 0; r < 4; ++r) {
      const float t1 = __builtin_fmaf(SD, eps[r], nb2.f[r]);
      P[r] = __builtin_fmaf(C0, xm[r], t1) * INV_NS;
    }

    // relu -> fp8 pack -> LDS (1 u32 write per t, lane-linear)
#pragma unroll
    for (int t = 0; t < 4; ++t) {
      f32x4 h;
#pragma unroll
      for (int r = 0; r < 4; ++r) h[r] = fmaxf(acc1[t][r], 0.f);
      u32 hw = cvt2_fp8<false>(h[0], h[1], 0u);
      hw     = cvt2_fp8<true >(h[2], h[3], hw);
      *(u32*)(hw_p + t * 256) = hw;
    }
    __syncthreads();   // publish h

    // ---- layer 2 (MX fp8, K=512): pure burst: 8 reads then 4 MFMAs.
    //      acc2[0] starts at P (update folded in), acc2[1] at 0 ----
    frag32 bh0, bh1, bh2, bh3;
    bh0.h[0] = *(const i32x4*)(rd_p);
    bh0.h[1] = *(const i32x4*)(rd_p + 256);
    bh1.h[0] = *(const i32x4*)(rd_p + 2048);
    bh1.h[1] = *(const i32x4*)(rd_p + 2048 + 256);
    bh2.h[0] = *(const i32x4*)(rd_p + 4096);
    bh2.h[1] = *(const i32x4*)(rd_p + 4096 + 256);
    bh3.h[0] = *(const i32x4*)(rd_p + 6144);
    bh3.h[1] = *(const i32x4*)(rd_p + 6144 + 256);
    f32x4 accA = P;
    f32x4 accB = (f32x4){0.f, 0.f, 0.f, 0.f};
    accA = __builtin_amdgcn_mfma_scale_f32_16x16x128_f8f6f4(
             a2s[0].v, bh0.v, accA, 0, 0, 0, SC1, 0, SC1);
    accB = __builtin_amdgcn_mfma_scale_f32_16x16x128_f8f6f4(
             a2s[1].v, bh1.v, accB, 0, 0, 0, SC1, 0, SC1);
    accA = __builtin_amdgcn_mfma_scale_f32_16x16x128_f8f6f4(
             a2s[2].v, bh2.v, accA, 0, 0, 0, SC1, 0, SC1);
    accB = __builtin_amdgcn_mfma_scale_f32_16x16x128_f8f6f4(
             a2s[3].v, bh3.v, accB, 0, 0, 0, SC1, 0, SC1);

    // ---- epilogue: xn = NS*(accA+accB); pack; publish x ----
    f32x4 xn;
#pragma unroll
    for (int r = 0; r < 4; ++r) xn[r] = NS * (accA[r] + accB[r]);
    xm = xn;
    {
      u32 xw0 = cvt2_fp8<false>(xn[0], xn[1], 0u);
      xw0     = cvt2_fp8<true >(xn[2], xn[3], xw0);
      *(u32*)xw_p = xw0;
    }
    __syncthreads();   // publish x

    // store AFTER the barrier: drains under next step's layer-1
    *(f32x4*)(out + obase + (NSTEPS - k) * LEN + l0) = xn;
  }
}

extern "C" void kernel_launch(void* const* d_in, const int* in_sizes, int n_in,
                              void* d_out, int out_size, void* d_ws, size_t ws_size,
                              hipStream_t stream) {
  const float* fd    = (const float*)d_in[0];
  const float* W1    = (const float*)d_in[1];
  const float* b1    = (const float*)d_in[2];
  const float* W2    = (const float*)d_in[3];
  const float* b2    = (const float*)d_in[4];
  const float* noise = (const float*)d_in[5];
  (void)in_sizes; (void)n_in; (void)out_size; (void)d_ws; (void)ws_size;
  cond_diff_kernel<<<dim3(32), dim3(512), 0, stream>>>(fd, W1, b1, W2, b2, noise,
                                                       (float*)d_out);
}